// Round 1
// baseline (303.645 us; speedup 1.0000x reference)
//
#include <hip/hip_runtime.h>
#include <hip/hip_bf16.h>
#include <stdint.h>

#define NN 4096
#define DD 512
#define NCLS 512
#define LMARGIN 0.3f

typedef float f32x4 __attribute__((ext_vector_type(4)));
typedef __bf16 bf16x8 __attribute__((ext_vector_type(8)));
typedef unsigned int u32;

// async global->LDS, 16B per lane. LDS dest is wave-uniform base + lane*16.
__device__ __forceinline__ void gld_lds16(const void* g, void* l) {
    __builtin_amdgcn_global_load_lds((const __attribute__((address_space(1))) u32*)g,
                                     (__attribute__((address_space(3))) u32*)l,
                                     16, 0, 0);
}

__device__ __forceinline__ float waveSum(float v) {
#pragma unroll
    for (int s = 32; s > 0; s >>= 1) v += __shfl_down(v, s, 64);
    return v;
}

// ---------- init workspace (ws is poisoned 0xAA before every launch) ----------
__global__ void k_init(float* __restrict__ classSum, float* __restrict__ classCnt,
                       u32* __restrict__ rmaxg, u32* __restrict__ rming,
                       float* __restrict__ sums) {
    int i = blockIdx.x * 256 + threadIdx.x;   // grid covers NCLS*DD = 262144
    classSum[i] = 0.f;
    if (i < NCLS) classCnt[i] = 0.f;
    if (i < NN) { rmaxg[i] = 0u; rming[i] = 0x7f800000u; }  // 0 / +inf
    if (i < 3) sums[i] = 0.f;
}

// ---------- per-row: bf16 cast, squared norm, class scatter ----------
__global__ void k_prep(const float* __restrict__ x, const int* __restrict__ tgt,
                       __hip_bfloat16* __restrict__ xb, float* __restrict__ sq,
                       int* __restrict__ tgt32, float* __restrict__ classSum,
                       float* __restrict__ classCnt) {
    int row = blockIdx.x, tid = threadIdx.x;  // 256 threads
    int t = tgt[row];
    float s = 0.f;
#pragma unroll
    for (int jj = 0; jj < 2; ++jj) {
        int d = tid + jj * 256;
        float v = x[(size_t)row * DD + d];
        xb[(size_t)row * DD + d] = __float2bfloat16(v);
        s += v * v;
        atomicAdd(&classSum[t * DD + d], v);
    }
    s = waveSum(s);
    __shared__ float red[4];
    if ((tid & 63) == 0) red[tid >> 6] = s;
    __syncthreads();
    if (tid == 0) {
        sq[row] = red[0] + red[1] + red[2] + red[3];
        tgt32[row] = t;
        atomicAdd(&classCnt[t], 1.f);
    }
}

// ---------- totalSum[d] = sum_c classSum[c][d] ----------
__global__ void k_totsum(const float* __restrict__ classSum, float* __restrict__ totalSum) {
    int d = blockIdx.x * 256 + threadIdx.x;   // grid 2 x 256 = 512 = DD
    float s = 0.f;
#pragma unroll 8
    for (int c = 0; c < NCLS; ++c) s += classSum[(size_t)c * DD + d];
    totalSum[d] = s;
}

// ---------- Gram matrix (bf16 MFMA) fused with masked row max/min ----------
__global__ __launch_bounds__(256) void k_gram(const __hip_bfloat16* __restrict__ xb,
                                              const float* __restrict__ sq,
                                              const int* __restrict__ tgt,
                                              u32* __restrict__ rmaxg,
                                              u32* __restrict__ rming) {
    const int bx = blockIdx.x, by = blockIdx.y;
    if (by > bx) return;   // symmetry: only upper triangle; update both row & col stats
    __shared__ __align__(16) __hip_bfloat16 As[128 * 32];
    __shared__ __align__(16) __hip_bfloat16 Bs[128 * 32];
    const int tid = threadIdx.x;
    const int lane = tid & 63, wave = tid >> 6;
    const int wr = wave >> 1, wc = wave & 1;
    const int l15 = lane & 15, quad = lane >> 4;
    const __hip_bfloat16* A0 = xb + (size_t)by * 128 * DD;
    const __hip_bfloat16* B0 = xb + (size_t)bx * 128 * DD;
    const int ldRow = tid >> 2;          // 0..63
    const int ldCol = (tid & 3) * 8;     // bf16 units
    char* AsB = (char*)As;
    char* BsB = (char*)Bs;
    const int ldsOff = wave * 1024;      // lane-contiguous 16B per thread

    f32x4 acc[4][4];
    const f32x4 fz = {0.f, 0.f, 0.f, 0.f};
#pragma unroll
    for (int i = 0; i < 4; ++i)
#pragma unroll
        for (int j = 0; j < 4; ++j) acc[i][j] = fz;

    for (int k0 = 0; k0 < DD; k0 += 32) {
        gld_lds16(A0 + (size_t)ldRow * DD + k0 + ldCol, AsB + ldsOff);
        gld_lds16(A0 + (size_t)(64 + ldRow) * DD + k0 + ldCol, AsB + 4096 + ldsOff);
        gld_lds16(B0 + (size_t)ldRow * DD + k0 + ldCol, BsB + ldsOff);
        gld_lds16(B0 + (size_t)(64 + ldRow) * DD + k0 + ldCol, BsB + 4096 + ldsOff);
        __syncthreads();
        bf16x8 af[4], bfr[4];
#pragma unroll
        for (int t = 0; t < 4; ++t)
            af[t] = *(const bf16x8*)(As + (wr * 64 + t * 16 + l15) * 32 + quad * 8);
#pragma unroll
        for (int t = 0; t < 4; ++t)
            bfr[t] = *(const bf16x8*)(Bs + (wc * 64 + t * 16 + l15) * 32 + quad * 8);
#pragma unroll
        for (int i = 0; i < 4; ++i)
#pragma unroll
            for (int j = 0; j < 4; ++j)
                acc[i][j] = __builtin_amdgcn_mfma_f32_16x16x32_bf16(af[i], bfr[j], acc[i][j], 0, 0, 0);
        __syncthreads();
    }

    // epilogue: dist = sqrt(max(sq[r]+sq[c]-2G, 1e-12)); masked max (same class) / min (diff)
    const int r0 = by * 128 + wr * 64;
    const int c0 = bx * 128 + wc * 64;
    float sqc[4];
    int tct[4];
#pragma unroll
    for (int j = 0; j < 4; ++j) {
        int c = c0 + j * 16 + l15;
        sqc[j] = sq[c];
        tct[j] = tgt[c];
    }
    float cmaxv[4], cminv[4];
#pragma unroll
    for (int j = 0; j < 4; ++j) { cmaxv[j] = 0.f; cminv[j] = __builtin_inff(); }

#pragma unroll
    for (int i = 0; i < 4; ++i) {
#pragma unroll
        for (int rg = 0; rg < 4; ++rg) {
            int r = r0 + i * 16 + quad * 4 + rg;
            float sqr = sq[r];
            int rt = tgt[r];
            float rmaxv = 0.f, rminv = __builtin_inff();
#pragma unroll
            for (int j = 0; j < 4; ++j) {
                float g = acc[i][j][rg];
                float dist = sqrtf(fmaxf(sqr + sqc[j] - 2.0f * g, 1e-12f));
                if (rt == tct[j]) {
                    rmaxv = fmaxf(rmaxv, dist);
                    cmaxv[j] = fmaxf(cmaxv[j], dist);
                } else {
                    rminv = fminf(rminv, dist);
                    cminv[j] = fminf(cminv[j], dist);
                }
            }
#pragma unroll
            for (int s = 1; s < 16; s <<= 1) {  // reduce across the 16 lanes of this quad
                rmaxv = fmaxf(rmaxv, __shfl_xor(rmaxv, s, 64));
                rminv = fminf(rminv, __shfl_xor(rminv, s, 64));
            }
            if (l15 == 0) {
                atomicMax(&rmaxg[r], __float_as_uint(rmaxv));
                atomicMin(&rming[r], __float_as_uint(rminv));
            }
        }
    }
    // column stats (transposed element): reduce across quads
#pragma unroll
    for (int j = 0; j < 4; ++j) {
        float vmax = cmaxv[j], vmin = cminv[j];
        vmax = fmaxf(vmax, __shfl_xor(vmax, 16, 64));
        vmax = fmaxf(vmax, __shfl_xor(vmax, 32, 64));
        vmin = fminf(vmin, __shfl_xor(vmin, 16, 64));
        vmin = fminf(vmin, __shfl_xor(vmin, 32, 64));
        if (quad == 0) {
            int c = c0 + j * 16 + l15;
            atomicMax(&rmaxg[c], __float_as_uint(vmax));
            atomicMin(&rming[c], __float_as_uint(vmin));
        }
    }
}

// ---------- per-row centroid losses + triplet accumulation ----------
__global__ void k_rowloss(const float* __restrict__ x, const int* __restrict__ tgt,
                          const float* __restrict__ classSum, const float* __restrict__ classCnt,
                          const float* __restrict__ totalSum, const u32* __restrict__ rmaxg,
                          const u32* __restrict__ rming, float* __restrict__ sums) {
    int i = blockIdx.x, tid = threadIdx.x;  // 256 threads
    int t = tgt[i];
    float cnt = classCnt[t];
    float scp = 0.f, scn = 0.f, scc = 0.f;
#pragma unroll
    for (int jj = 0; jj < 2; ++jj) {
        int d = tid + jj * 256;
        float xv = x[(size_t)i * DD + d];
        float cs = classSum[t * DD + d];
        float ts = totalSum[d];
        float ic = cs / cnt;
        float oc = (ts - cs) / ((float)NN - cnt);
        float a = ic - xv, b = oc - xv, c = ic - oc;
        scp += a * a;
        scn += b * b;
        scc += c * c;
    }
    scp = waveSum(scp);
    scn = waveSum(scn);
    scc = waveSum(scc);
    __shared__ float red[4][3];
    int w = tid >> 6;
    if ((tid & 63) == 0) { red[w][0] = scp; red[w][1] = scn; red[w][2] = scc; }
    __syncthreads();
    if (tid == 0) {
        float p = red[0][0] + red[1][0] + red[2][0] + red[3][0];
        float n2 = red[0][1] + red[1][1] + red[2][1] + red[3][1];
        float cc = red[0][2] + red[1][2] + red[2][2] + red[3][2];
        float dcp = sqrtf(p), dcn = sqrtf(n2), dcc = sqrtf(cc);
        float ctl = fmaxf(dcp - dcn + LMARGIN, 0.f);
        float ap = __uint_as_float(rmaxg[i]);
        float an = __uint_as_float(rming[i]);
        float tl = fmaxf(ap - an + LMARGIN, 0.f);
        atomicAdd(&sums[0], tl);
        atomicAdd(&sums[1], ctl);
        atomicAdd(&sums[2], dcc);
    }
}

__global__ void k_final(const float* __restrict__ sums, float* __restrict__ out) {
    if (threadIdx.x == 0) {
        out[0] = sums[0] * (1.0f / NN);
        out[1] = sums[1] * (1.0f / NN);
        out[2] = -sums[2] * (1.0f / NN);
    }
}

extern "C" void kernel_launch(void* const* d_in, const int* in_sizes, int n_in,
                              void* d_out, int out_size, void* d_ws, size_t ws_size,
                              hipStream_t stream) {
    const float* x = (const float*)d_in[0];
    const int* tgt = (const int*)d_in[1];
    float* out = (float*)d_out;
    char* ws = (char*)d_ws;

    size_t o = 0;
    __hip_bfloat16* xb = (__hip_bfloat16*)(ws + o); o += (size_t)NN * DD * 2;  // 4 MB
    float* sq = (float*)(ws + o);       o += (size_t)NN * 4;
    int* tgt32 = (int*)(ws + o);        o += (size_t)NN * 4;
    float* classSum = (float*)(ws + o); o += (size_t)NCLS * DD * 4;            // 1 MB
    float* classCnt = (float*)(ws + o); o += (size_t)NCLS * 4;
    float* totalSum = (float*)(ws + o); o += (size_t)DD * 4;
    u32* rmaxg = (u32*)(ws + o);        o += (size_t)NN * 4;
    u32* rming = (u32*)(ws + o);        o += (size_t)NN * 4;
    float* sums = (float*)(ws + o);     o += 16;

    k_init<<<dim3((NCLS * DD) / 256), dim3(256), 0, stream>>>(classSum, classCnt, rmaxg, rming, sums);
    k_prep<<<dim3(NN), dim3(256), 0, stream>>>(x, tgt, xb, sq, tgt32, classSum, classCnt);
    k_totsum<<<dim3(2), dim3(256), 0, stream>>>(classSum, totalSum);
    k_gram<<<dim3(32, 32), dim3(256), 0, stream>>>(xb, sq, tgt32, rmaxg, rming);
    k_rowloss<<<dim3(NN), dim3(256), 0, stream>>>(x, tgt32, classSum, classCnt, totalSum, rmaxg, rming, sums);
    k_final<<<dim3(1), dim3(64), 0, stream>>>(sums, out);
}

// Round 2
// 153.713 us; speedup vs baseline: 1.9754x; 1.9754x over previous
//
#include <hip/hip_runtime.h>
#include <hip/hip_bf16.h>
#include <stdint.h>

#define NN 4096
#define DD 512
#define NCLS 512
#define LMARGIN 0.3f

typedef float f32x4 __attribute__((ext_vector_type(4)));
typedef __bf16 bf16x8 __attribute__((ext_vector_type(8)));
typedef unsigned int u32;

// async global->LDS, 16B per lane. LDS dest is wave-uniform base + lane*16.
__device__ __forceinline__ void gld_lds16(const void* g, void* l) {
    __builtin_amdgcn_global_load_lds((const __attribute__((address_space(1))) u32*)g,
                                     (__attribute__((address_space(3))) u32*)l,
                                     16, 0, 0);
}

__device__ __forceinline__ float waveSum(float v) {
#pragma unroll
    for (int s = 32; s > 0; s >>= 1) v += __shfl_down(v, s, 64);
    return v;
}

// ---------- init workspace (ws is poisoned 0xAA before every launch) ----------
__global__ void k_init(float* __restrict__ classSum, float* __restrict__ classCnt,
                       u32* __restrict__ rmaxg, u32* __restrict__ rming) {
    int i = blockIdx.x * 256 + threadIdx.x;   // grid covers NCLS*DD = 262144
    classSum[i] = 0.f;
    if (i < NCLS) classCnt[i] = 0.f;
    if (i < NN) { rmaxg[i] = 0u; rming[i] = 0x7f800000u; }  // 0 / +inf
}

// ---------- per-row: bf16 cast, squared norm, class scatter ----------
__global__ void k_prep(const float* __restrict__ x, const int* __restrict__ tgt,
                       __hip_bfloat16* __restrict__ xb, float* __restrict__ sq,
                       int* __restrict__ tgt32, float* __restrict__ classSum,
                       float* __restrict__ classCnt) {
    int row = blockIdx.x, tid = threadIdx.x;  // 256 threads
    int t = tgt[row];
    float s = 0.f;
#pragma unroll
    for (int jj = 0; jj < 2; ++jj) {
        int d = tid + jj * 256;
        float v = x[(size_t)row * DD + d];
        xb[(size_t)row * DD + d] = __float2bfloat16(v);
        s += v * v;
        atomicAdd(&classSum[t * DD + d], v);
    }
    s = waveSum(s);
    __shared__ float red[4];
    if ((tid & 63) == 0) red[tid >> 6] = s;
    __syncthreads();
    if (tid == 0) {
        sq[row] = red[0] + red[1] + red[2] + red[3];
        tgt32[row] = t;
        atomicAdd(&classCnt[t], 1.f);
    }
}

// ---------- totalSum[d] = sum_c classSum[c][d] ----------
__global__ void k_totsum(const float* __restrict__ classSum, float* __restrict__ totalSum) {
    int d = blockIdx.x * 256 + threadIdx.x;   // grid 2 x 256 = 512 = DD
    float s = 0.f;
#pragma unroll 8
    for (int c = 0; c < NCLS; ++c) s += classSum[(size_t)c * DD + d];
    totalSum[d] = s;
}

// ---------- Gram matrix (bf16 MFMA) fused with masked row max/min ----------
__global__ __launch_bounds__(256) void k_gram(const __hip_bfloat16* __restrict__ xb,
                                              const float* __restrict__ sq,
                                              const int* __restrict__ tgt,
                                              u32* __restrict__ rmaxg,
                                              u32* __restrict__ rming) {
    const int bx = blockIdx.x, by = blockIdx.y;
    if (by > bx) return;   // symmetry: only upper triangle; update both row & col stats
    __shared__ __align__(16) __hip_bfloat16 As[128 * 32];
    __shared__ __align__(16) __hip_bfloat16 Bs[128 * 32];
    const int tid = threadIdx.x;
    const int lane = tid & 63, wave = tid >> 6;
    const int wr = wave >> 1, wc = wave & 1;
    const int l15 = lane & 15, quad = lane >> 4;
    const __hip_bfloat16* A0 = xb + (size_t)by * 128 * DD;
    const __hip_bfloat16* B0 = xb + (size_t)bx * 128 * DD;
    const int ldRow = tid >> 2;          // 0..63
    const int ldCol = (tid & 3) * 8;     // bf16 units
    char* AsB = (char*)As;
    char* BsB = (char*)Bs;
    const int ldsOff = wave * 1024;      // lane-contiguous 16B per thread

    f32x4 acc[4][4];
    const f32x4 fz = {0.f, 0.f, 0.f, 0.f};
#pragma unroll
    for (int i = 0; i < 4; ++i)
#pragma unroll
        for (int j = 0; j < 4; ++j) acc[i][j] = fz;

    for (int k0 = 0; k0 < DD; k0 += 32) {
        gld_lds16(A0 + (size_t)ldRow * DD + k0 + ldCol, AsB + ldsOff);
        gld_lds16(A0 + (size_t)(64 + ldRow) * DD + k0 + ldCol, AsB + 4096 + ldsOff);
        gld_lds16(B0 + (size_t)ldRow * DD + k0 + ldCol, BsB + ldsOff);
        gld_lds16(B0 + (size_t)(64 + ldRow) * DD + k0 + ldCol, BsB + 4096 + ldsOff);
        __syncthreads();
        bf16x8 af[4], bfr[4];
#pragma unroll
        for (int t = 0; t < 4; ++t)
            af[t] = *(const bf16x8*)(As + (wr * 64 + t * 16 + l15) * 32 + quad * 8);
#pragma unroll
        for (int t = 0; t < 4; ++t)
            bfr[t] = *(const bf16x8*)(Bs + (wc * 64 + t * 16 + l15) * 32 + quad * 8);
#pragma unroll
        for (int i = 0; i < 4; ++i)
#pragma unroll
            for (int j = 0; j < 4; ++j)
                acc[i][j] = __builtin_amdgcn_mfma_f32_16x16x32_bf16(af[i], bfr[j], acc[i][j], 0, 0, 0);
        __syncthreads();
    }

    // epilogue: dist = sqrt(max(sq[r]+sq[c]-2G, 1e-12)); masked max (same class) / min (diff)
    const int r0 = by * 128 + wr * 64;
    const int c0 = bx * 128 + wc * 64;
    float sqc[4];
    int tct[4];
#pragma unroll
    for (int j = 0; j < 4; ++j) {
        int c = c0 + j * 16 + l15;
        sqc[j] = sq[c];
        tct[j] = tgt[c];
    }
    float cmaxv[4], cminv[4];
#pragma unroll
    for (int j = 0; j < 4; ++j) { cmaxv[j] = 0.f; cminv[j] = __builtin_inff(); }

#pragma unroll
    for (int i = 0; i < 4; ++i) {
#pragma unroll
        for (int rg = 0; rg < 4; ++rg) {
            int r = r0 + i * 16 + quad * 4 + rg;
            float sqr = sq[r];
            int rt = tgt[r];
            float rmaxv = 0.f, rminv = __builtin_inff();
#pragma unroll
            for (int j = 0; j < 4; ++j) {
                float g = acc[i][j][rg];
                float dist = sqrtf(fmaxf(sqr + sqc[j] - 2.0f * g, 1e-12f));
                if (rt == tct[j]) {
                    rmaxv = fmaxf(rmaxv, dist);
                    cmaxv[j] = fmaxf(cmaxv[j], dist);
                } else {
                    rminv = fminf(rminv, dist);
                    cminv[j] = fminf(cminv[j], dist);
                }
            }
#pragma unroll
            for (int s = 1; s < 16; s <<= 1) {  // reduce across the 16 lanes of this quad
                rmaxv = fmaxf(rmaxv, __shfl_xor(rmaxv, s, 64));
                rminv = fminf(rminv, __shfl_xor(rminv, s, 64));
            }
            if (l15 == 0) {
                atomicMax(&rmaxg[r], __float_as_uint(rmaxv));
                atomicMin(&rming[r], __float_as_uint(rminv));
            }
        }
    }
    // column stats (transposed element): reduce across quads
#pragma unroll
    for (int j = 0; j < 4; ++j) {
        float vmax = cmaxv[j], vmin = cminv[j];
        vmax = fmaxf(vmax, __shfl_xor(vmax, 16, 64));
        vmax = fmaxf(vmax, __shfl_xor(vmax, 32, 64));
        vmin = fminf(vmin, __shfl_xor(vmin, 16, 64));
        vmin = fminf(vmin, __shfl_xor(vmin, 32, 64));
        if (quad == 0) {
            int c = c0 + j * 16 + l15;
            atomicMax(&rmaxg[c], __float_as_uint(vmax));
            atomicMin(&rming[c], __float_as_uint(vmin));
        }
    }
}

// ---------- per-row centroid losses + triplet terms (NO global atomics) ----------
__global__ void k_rowloss(const float* __restrict__ x, const int* __restrict__ tgt,
                          const float* __restrict__ classSum, const float* __restrict__ classCnt,
                          const float* __restrict__ totalSum, const u32* __restrict__ rmaxg,
                          const u32* __restrict__ rming,
                          float* __restrict__ tlArr, float* __restrict__ ctlArr,
                          float* __restrict__ dccArr) {
    int i = blockIdx.x, tid = threadIdx.x;  // 256 threads
    int t = tgt[i];
    float cnt = classCnt[t];
    float rcp = 1.0f / cnt;
    float rcn = 1.0f / ((float)NN - cnt);
    float scp = 0.f, scn = 0.f, scc = 0.f;
#pragma unroll
    for (int jj = 0; jj < 2; ++jj) {
        int d = tid + jj * 256;
        float xv = x[(size_t)i * DD + d];
        float cs = classSum[t * DD + d];
        float ts = totalSum[d];
        float ic = cs * rcp;
        float oc = (ts - cs) * rcn;
        float a = ic - xv, b = oc - xv, c = ic - oc;
        scp += a * a;
        scn += b * b;
        scc += c * c;
    }
    scp = waveSum(scp);
    scn = waveSum(scn);
    scc = waveSum(scc);
    __shared__ float red[4][3];
    int w = tid >> 6;
    if ((tid & 63) == 0) { red[w][0] = scp; red[w][1] = scn; red[w][2] = scc; }
    __syncthreads();
    if (tid == 0) {
        float p = red[0][0] + red[1][0] + red[2][0] + red[3][0];
        float n2 = red[0][1] + red[1][1] + red[2][1] + red[3][1];
        float cc = red[0][2] + red[1][2] + red[2][2] + red[3][2];
        float dcp = sqrtf(p), dcn = sqrtf(n2), dcc = sqrtf(cc);
        float ap = __uint_as_float(rmaxg[i]);
        float an = __uint_as_float(rming[i]);
        tlArr[i] = fmaxf(ap - an + LMARGIN, 0.f);
        ctlArr[i] = fmaxf(dcp - dcn + LMARGIN, 0.f);
        dccArr[i] = dcc;
    }
}

// ---------- single-block final reduction over 3 x NN values ----------
__global__ __launch_bounds__(1024) void k_reduce(const float* __restrict__ tlArr,
                                                 const float* __restrict__ ctlArr,
                                                 const float* __restrict__ dccArr,
                                                 float* __restrict__ out) {
    int tid = threadIdx.x;  // 1024 threads
    float s0 = 0.f, s1 = 0.f, s2 = 0.f;
#pragma unroll
    for (int jj = 0; jj < NN / 1024; ++jj) {
        int i = tid + jj * 1024;
        s0 += tlArr[i];
        s1 += ctlArr[i];
        s2 += dccArr[i];
    }
    s0 = waveSum(s0);
    s1 = waveSum(s1);
    s2 = waveSum(s2);
    __shared__ float red[16][3];
    int w = tid >> 6;
    if ((tid & 63) == 0) { red[w][0] = s0; red[w][1] = s1; red[w][2] = s2; }
    __syncthreads();
    if (tid == 0) {
        float a = 0.f, b = 0.f, c = 0.f;
#pragma unroll
        for (int k = 0; k < 16; ++k) { a += red[k][0]; b += red[k][1]; c += red[k][2]; }
        out[0] = a * (1.0f / NN);
        out[1] = b * (1.0f / NN);
        out[2] = -c * (1.0f / NN);
    }
}

extern "C" void kernel_launch(void* const* d_in, const int* in_sizes, int n_in,
                              void* d_out, int out_size, void* d_ws, size_t ws_size,
                              hipStream_t stream) {
    const float* x = (const float*)d_in[0];
    const int* tgt = (const int*)d_in[1];
    float* out = (float*)d_out;
    char* ws = (char*)d_ws;

    size_t o = 0;
    __hip_bfloat16* xb = (__hip_bfloat16*)(ws + o); o += (size_t)NN * DD * 2;  // 4 MB
    float* sq = (float*)(ws + o);       o += (size_t)NN * 4;
    int* tgt32 = (int*)(ws + o);        o += (size_t)NN * 4;
    float* classSum = (float*)(ws + o); o += (size_t)NCLS * DD * 4;            // 1 MB
    float* classCnt = (float*)(ws + o); o += (size_t)NCLS * 4;
    float* totalSum = (float*)(ws + o); o += (size_t)DD * 4;
    u32* rmaxg = (u32*)(ws + o);        o += (size_t)NN * 4;
    u32* rming = (u32*)(ws + o);        o += (size_t)NN * 4;
    float* tlArr = (float*)(ws + o);    o += (size_t)NN * 4;
    float* ctlArr = (float*)(ws + o);   o += (size_t)NN * 4;
    float* dccArr = (float*)(ws + o);   o += (size_t)NN * 4;

    k_init<<<dim3((NCLS * DD) / 256), dim3(256), 0, stream>>>(classSum, classCnt, rmaxg, rming);
    k_prep<<<dim3(NN), dim3(256), 0, stream>>>(x, tgt, xb, sq, tgt32, classSum, classCnt);
    k_totsum<<<dim3(2), dim3(256), 0, stream>>>(classSum, totalSum);
    k_gram<<<dim3(32, 32), dim3(256), 0, stream>>>(xb, sq, tgt32, rmaxg, rming);
    k_rowloss<<<dim3(NN), dim3(256), 0, stream>>>(x, tgt32, classSum, classCnt, totalSum, rmaxg, rming,
                                                  tlArr, ctlArr, dccArr);
    k_reduce<<<dim3(1), dim3(1024), 0, stream>>>(tlArr, ctlArr, dccArr, out);
}